// Round 2
// baseline (537.451 us; speedup 1.0000x reference)
//
#include <hip/hip_runtime.h>
#include <stdint.h>

#define NN 30000
#define NE 480000

// ------------------------- compile-time Clebsch-Gordan -------------------------
constexpr double cfact(int n){ double r=1.0; for(int i=2;i<=n;i++) r*=(double)i; return r; }
constexpr double csqrt_(double x){ if(x<=0.0) return 0.0; double g = x<1.0?1.0:x; for(int i=0;i<200;i++) g = 0.5*(g + x/g); return g; }
constexpr double cg_coeff(int j1,int m1,int j2,int m2,int j,int m){
  if(m != m1+m2) return 0.0;
  int dj = j1-j2; if(dj<0) dj=-dj;
  if(j < dj || j > j1+j2) return 0.0;
  double pre = csqrt_((2*j+1)*cfact(j+j1-j2)*cfact(j-j1+j2)*cfact(j1+j2-j)/cfact(j1+j2+j+1));
  pre = pre * csqrt_(cfact(j+m)*cfact(j-m)*cfact(j1-m1)*cfact(j1+m1)*cfact(j2-m2)*cfact(j2+m2));
  double s = 0.0;
  for(int k=0;k<=j1+j2-j;k++){
    int d0=k, d1=j1+j2-j-k, d2=j1-m1-k, d3=j2+m2-k, d4=j-j2+m1+k, d5=j-j1-m2+k;
    if(d0<0||d1<0||d2<0||d3<0||d4<0||d5<0) continue;
    double term = 1.0/(cfact(d0)*cfact(d1)*cfact(d2)*cfact(d3)*cfact(d4)*cfact(d5));
    s += (k&1) ? -term : term;
  }
  return pre*s;
}

template<int L1,int L2,int LO> struct CGTab { float v[2*LO+1][2*L1+1][2*L2+1]; };

template<int L1,int L2,int LO>
constexpr CGTab<L1,L2,LO> make_cg(){
  CGTab<L1,L2,LO> t{};
  for(int m=-LO;m<=LO;m++)
    for(int p=-L1;p<=L1;p++)
      for(int q=-L2;q<=L2;q++)
        t.v[m+LO][p+L1][q+L2] = (float)cg_coeff(L1,p,L2,q,LO,m);
  return t;
}
template<int L1,int L2,int LO>
constexpr CGTab<L1,L2,LO> CG_TAB = make_cg<L1,L2,LO>();

// ------------------------- CG chunk: T = C : (a x b), acc += W^T T -------------------------
// A: CA channels, stride 2*L1+1. B: CB channels, stride 2*L2+1.
// W row-major (rows = cat-channels, 8 outputs); row index = wb + c*CB + d.
template<int L1,int L2,int LO,int CA,int CB>
__device__ __forceinline__ void do_chunk(const float* __restrict__ A,
                                         const float* __restrict__ B,
                                         const float* __restrict__ W, int wb,
                                         float acc[8][2*LO+1])
{
  constexpr int MA=2*L1+1, MB=2*L2+1, MO=2*LO+1;
  #pragma unroll 1
  for(int c=0;c<CA;c++){
    float av[MA];
    #pragma unroll
    for(int p=0;p<MA;p++) av[p]=A[c*MA+p];
    #pragma unroll 1
    for(int d=0;d<CB;d++){
      float bv[MB];
      #pragma unroll
      for(int q=0;q<MB;q++) bv[q]=B[d*MB+q];
      float T[MO];
      #pragma unroll
      for(int m=0;m<MO;m++) T[m]=0.f;
      #pragma unroll
      for(int m=0;m<MO;m++){
        #pragma unroll
        for(int p=0;p<MA;p++){
          #pragma unroll
          for(int q=0;q<MB;q++){
            const float cg = CG_TAB<L1,L2,LO>.v[m][p][q];   // compile-time const after unroll
            if(cg != 0.0f) T[m] = fmaf(cg*av[p], bv[q], T[m]);
          }
        }
      }
      const float* wr = W + (wb + c*CB + d)*8;               // wave-uniform -> scalar loads
      #pragma unroll
      for(int o=0;o<8;o++){
        float w = wr[o];
        #pragma unroll
        for(int m=0;m<MO;m++) acc[o][m] = fmaf(w, T[m], acc[o][m]);
      }
    }
  }
}

// Run all CG chunks for one product at output order LO. a* / b* are the l=0,1,2
// pointers of the A and B operands (CA / CB channels each).
template<int LO,int CA,int CB>
__device__ __forceinline__ void run_chunks(
    const float* a0,const float* a1,const float* a2,
    const float* b0,const float* b1,const float* b2,
    const float* __restrict__ W, float acc[8][2*LO+1])
{
  int wb=0;
  if constexpr (LO==0){
    do_chunk<0,0,0,CA,CB>(a0,b0,W,wb,acc); wb+=CA*CB;
    do_chunk<1,1,0,CA,CB>(a1,b1,W,wb,acc); wb+=CA*CB;
    do_chunk<2,2,0,CA,CB>(a2,b2,W,wb,acc);
  } else if constexpr (LO==1){
    do_chunk<0,1,1,CA,CB>(a0,b1,W,wb,acc); wb+=CA*CB;
    do_chunk<1,0,1,CA,CB>(a1,b0,W,wb,acc); wb+=CA*CB;
    do_chunk<1,1,1,CA,CB>(a1,b1,W,wb,acc); wb+=CA*CB;
    do_chunk<1,2,1,CA,CB>(a1,b2,W,wb,acc); wb+=CA*CB;
    do_chunk<2,1,1,CA,CB>(a2,b1,W,wb,acc); wb+=CA*CB;
    do_chunk<2,2,1,CA,CB>(a2,b2,W,wb,acc);
  } else {
    do_chunk<0,2,2,CA,CB>(a0,b2,W,wb,acc); wb+=CA*CB;
    do_chunk<1,1,2,CA,CB>(a1,b1,W,wb,acc); wb+=CA*CB;
    do_chunk<1,2,2,CA,CB>(a1,b2,W,wb,acc); wb+=CA*CB;
    do_chunk<2,0,2,CA,CB>(a2,b0,W,wb,acc); wb+=CA*CB;
    do_chunk<2,1,2,CA,CB>(a2,b1,W,wb,acc); wb+=CA*CB;
    do_chunk<2,2,2,CA,CB>(a2,b2,W,wb,acc);
  }
}

// One thread = one (node, LO): all three products summed, written once (no atomics).
template<int LO>
__device__ __forceinline__ void do_lo(int node,
    const float* __restrict__ x0,const float* __restrict__ x1,const float* __restrict__ x2,
    const float* __restrict__ y,
    const float* __restrict__ Wyy,const float* __restrict__ Wyx,const float* __restrict__ Wxx,
    float* __restrict__ out)
{
  const float* y0 = y + node*72;      // 8 ch x 1
  const float* y1 = y0 + 8;           // 8 ch x 3
  const float* y2 = y0 + 32;          // 8 ch x 5
  const float* xa0 = x0 + node*4;     // 4 ch x 1
  const float* xa1 = x1 + node*12;    // 4 ch x 3
  const float* xa2 = x2 + node*20;    // 4 ch x 5

  float acc[8][2*LO+1];
  #pragma unroll
  for(int o=0;o<8;o++)
    #pragma unroll
    for(int m=0;m<2*LO+1;m++) acc[o][m]=0.f;

  run_chunks<LO,8,8>(y0,y1,y2,  y0,y1,y2,  Wyy, acc);   // y (x) y
  run_chunks<LO,8,4>(y0,y1,y2,  xa0,xa1,xa2, Wyx, acc); // y (x) x
  run_chunks<LO,4,4>(xa0,xa1,xa2, xa0,xa1,xa2, Wxx, acc); // x (x) x

  constexpr int BASE = (LO==0)?0:((LO==1)?NN*8:NN*32);
  float* op = out + BASE + node*8*(2*LO+1);
  #pragma unroll
  for(int o=0;o<8;o++)
    #pragma unroll
    for(int m=0;m<2*LO+1;m++) op[o*(2*LO+1)+m] = acc[o][m];
}

struct WPtrs {
  const float* xx[3];
  const float* yx[3];
  const float* yy[3];
};

__global__ __launch_bounds__(256) void cg_kernel(
    const float* __restrict__ x0,const float* __restrict__ x1,const float* __restrict__ x2,
    const float* __restrict__ y, WPtrs w, float* __restrict__ out)
{
  int node = blockIdx.x*256 + threadIdx.x;
  if(node >= NN) return;
  switch(blockIdx.y){
    case 0: do_lo<2>(node,x0,x1,x2,y,w.yy[2],w.yx[2],w.xx[2],out); break;
    case 1: do_lo<1>(node,x0,x1,x2,y,w.yy[1],w.yx[1],w.xx[1],out); break;
    case 2: do_lo<0>(node,x0,x1,x2,y,w.yy[0],w.yx[0],w.xx[0],out); break;
  }
}

// ------------------------- message passing: scatter-add with atomics -------------------------
// y layout per node (72 floats): [ech*4+c] order -> l0: 8@0, l1: 8x3@8, l2: 8x5@32
__global__ __launch_bounds__(256) void mp_kernel(
  const float* __restrict__ x0, const float* __restrict__ x1,
  const float* __restrict__ x2, const float* __restrict__ ev,
  const int* __restrict__ idx, float* __restrict__ y)
{
  int t = blockIdx.x*256 + threadIdx.x;      // over NE*36
  if(t >= NE*36) return;
  int e = t/36, j = t - e*36;
  int src = idx[e], dst = idx[NE + e];
  float e0 = ev[2*e];
  float e1 = ev[2*e+1];
  float xv; int off, d1;
  if(j<4)       {            xv = x0[src*4  + j]; off = j;      d1 = 4;  }
  else if(j<16) { int r=j-4; xv = x1[src*12 + r]; off = 8 + r;  d1 = 12; }
  else          { int r=j-16;xv = x2[src*20 + r]; off = 32 + r; d1 = 20; }
  float* yn = y + dst*72;
  atomicAdd(yn + off,      e0*xv);
  atomicAdd(yn + off + d1, e1*xv);
}

extern "C" void kernel_launch(void* const* d_in, const int* in_sizes, int n_in,
                              void* d_out, int out_size, void* d_ws, size_t ws_size,
                              hipStream_t stream)
{
  const float* x0 = (const float*)d_in[0];
  const float* x1 = (const float*)d_in[1];
  const float* x2 = (const float*)d_in[2];
  const float* ev = (const float*)d_in[3];
  const int* idx  = (const int*)d_in[13];

  WPtrs w;
  for(int l=0;l<3;l++){
    w.xx[l] = (const float*)d_in[4+l];
    w.yx[l] = (const float*)d_in[7+l];
    w.yy[l] = (const float*)d_in[10+l];
  }

  float* y = (float*)d_ws;   // NN*72 floats = 8.64 MB
  hipMemsetAsync(y, 0, (size_t)NN*72*sizeof(float), stream);

  mp_kernel<<<(NE*36+255)/256, 256, 0, stream>>>(x0, x1, x2, ev, idx, y);

  dim3 g((NN+255)/256, 3);
  cg_kernel<<<g, 256, 0, stream>>>(x0, x1, x2, y, w, (float*)d_out);
}

// Round 3
// 467.020 us; speedup vs baseline: 1.1508x; 1.1508x over previous
//
#include <hip/hip_runtime.h>
#include <stdint.h>

#define NN 30000
#define NE 480000

// ------------------------- compile-time Clebsch-Gordan -------------------------
constexpr double cfact(int n){ double r=1.0; for(int i=2;i<=n;i++) r*=(double)i; return r; }
constexpr double csqrt_(double x){ if(x<=0.0) return 0.0; double g = x<1.0?1.0:x; for(int i=0;i<200;i++) g = 0.5*(g + x/g); return g; }
constexpr double cg_coeff(int j1,int m1,int j2,int m2,int j,int m){
  if(m != m1+m2) return 0.0;
  int dj = j1-j2; if(dj<0) dj=-dj;
  if(j < dj || j > j1+j2) return 0.0;
  double pre = csqrt_((2*j+1)*cfact(j+j1-j2)*cfact(j-j1+j2)*cfact(j1+j2-j)/cfact(j1+j2+j+1));
  pre = pre * csqrt_(cfact(j+m)*cfact(j-m)*cfact(j1-m1)*cfact(j1+m1)*cfact(j2-m2)*cfact(j2+m2));
  double s = 0.0;
  for(int k=0;k<=j1+j2-j;k++){
    int d0=k, d1=j1+j2-j-k, d2=j1-m1-k, d3=j2+m2-k, d4=j-j2+m1+k, d5=j-j1-m2+k;
    if(d0<0||d1<0||d2<0||d3<0||d4<0||d5<0) continue;
    double term = 1.0/(cfact(d0)*cfact(d1)*cfact(d2)*cfact(d3)*cfact(d4)*cfact(d5));
    s += (k&1) ? -term : term;
  }
  return pre*s;
}

template<int L1,int L2,int LO> struct CGTab { float v[2*LO+1][2*L1+1][2*L2+1]; };

template<int L1,int L2,int LO>
constexpr CGTab<L1,L2,LO> make_cg(){
  CGTab<L1,L2,LO> t{};
  for(int m=-LO;m<=LO;m++)
    for(int p=-L1;p<=L1;p++)
      for(int q=-L2;q<=L2;q++)
        t.v[m+LO][p+L1][q+L2] = (float)cg_coeff(L1,p,L2,q,LO,m);
  return t;
}
template<int L1,int L2,int LO>
constexpr CGTab<L1,L2,LO> CG_TAB = make_cg<L1,L2,LO>();

// ------------------------- CG chunk: T = C : (a x b), acc += W^T T -------------------------
template<int L1,int L2,int LO,int CA,int CB>
__device__ __forceinline__ void do_chunk(const float* __restrict__ A,
                                         const float* __restrict__ B,
                                         const float* __restrict__ W, int wb,
                                         float acc[8][2*LO+1])
{
  constexpr int MA=2*L1+1, MB=2*L2+1, MO=2*LO+1;
  #pragma unroll 1
  for(int c=0;c<CA;c++){
    float av[MA];
    #pragma unroll
    for(int p=0;p<MA;p++) av[p]=A[c*MA+p];
    #pragma unroll 1
    for(int d=0;d<CB;d++){
      float bv[MB];
      #pragma unroll
      for(int q=0;q<MB;q++) bv[q]=B[d*MB+q];
      float T[MO];
      #pragma unroll
      for(int m=0;m<MO;m++) T[m]=0.f;
      #pragma unroll
      for(int m=0;m<MO;m++){
        #pragma unroll
        for(int p=0;p<MA;p++){
          #pragma unroll
          for(int q=0;q<MB;q++){
            const float cg = CG_TAB<L1,L2,LO>.v[m][p][q];   // compile-time const after unroll
            if(cg != 0.0f) T[m] = fmaf(cg*av[p], bv[q], T[m]);
          }
        }
      }
      const float* wr = W + (wb + c*CB + d)*8;               // wave-uniform -> scalar loads
      #pragma unroll
      for(int o=0;o<8;o++){
        float w = wr[o];
        #pragma unroll
        for(int m=0;m<MO;m++) acc[o][m] = fmaf(w, T[m], acc[o][m]);
      }
    }
  }
}

template<int LO,int CA,int CB>
__device__ __forceinline__ void run_chunks(
    const float* a0,const float* a1,const float* a2,
    const float* b0,const float* b1,const float* b2,
    const float* __restrict__ W, float acc[8][2*LO+1])
{
  int wb=0;
  if constexpr (LO==0){
    do_chunk<0,0,0,CA,CB>(a0,b0,W,wb,acc); wb+=CA*CB;
    do_chunk<1,1,0,CA,CB>(a1,b1,W,wb,acc); wb+=CA*CB;
    do_chunk<2,2,0,CA,CB>(a2,b2,W,wb,acc);
  } else if constexpr (LO==1){
    do_chunk<0,1,1,CA,CB>(a0,b1,W,wb,acc); wb+=CA*CB;
    do_chunk<1,0,1,CA,CB>(a1,b0,W,wb,acc); wb+=CA*CB;
    do_chunk<1,1,1,CA,CB>(a1,b1,W,wb,acc); wb+=CA*CB;
    do_chunk<1,2,1,CA,CB>(a1,b2,W,wb,acc); wb+=CA*CB;
    do_chunk<2,1,1,CA,CB>(a2,b1,W,wb,acc); wb+=CA*CB;
    do_chunk<2,2,1,CA,CB>(a2,b2,W,wb,acc);
  } else {
    do_chunk<0,2,2,CA,CB>(a0,b2,W,wb,acc); wb+=CA*CB;
    do_chunk<1,1,2,CA,CB>(a1,b1,W,wb,acc); wb+=CA*CB;
    do_chunk<1,2,2,CA,CB>(a1,b2,W,wb,acc); wb+=CA*CB;
    do_chunk<2,0,2,CA,CB>(a2,b0,W,wb,acc); wb+=CA*CB;
    do_chunk<2,1,2,CA,CB>(a2,b1,W,wb,acc); wb+=CA*CB;
    do_chunk<2,2,2,CA,CB>(a2,b2,W,wb,acc);
  }
}

// One thread = one (node, PROD, LO). Writes its product's partial buffer (out layout).
template<int PROD,int LO>
__device__ __forceinline__ void do_item(int node,
    const float* __restrict__ x0,const float* __restrict__ x1,const float* __restrict__ x2,
    const float* __restrict__ y, const float* __restrict__ W, float* __restrict__ p)
{
  constexpr int CA = (PROD==2)?4:8;
  constexpr int CB = (PROD==0)?8:4;
  const float *a0,*a1,*a2,*b0,*b1,*b2;
  if constexpr (PROD==2){ a0 = x0 + node*4; a1 = x1 + node*12; a2 = x2 + node*20; }
  else                  { a0 = y + node*72; a1 = a0 + 8; a2 = a0 + 32; }
  if constexpr (PROD==0){ b0 = y + node*72; b1 = b0 + 8; b2 = b0 + 32; }
  else                  { b0 = x0 + node*4; b1 = x1 + node*12; b2 = x2 + node*20; }

  float acc[8][2*LO+1];
  #pragma unroll
  for(int o=0;o<8;o++)
    #pragma unroll
    for(int m=0;m<2*LO+1;m++) acc[o][m]=0.f;

  run_chunks<LO,CA,CB>(a0,a1,a2,b0,b1,b2,W,acc);

  constexpr int BASE = (LO==0)?0:((LO==1)?NN*8:NN*32);
  float* op = p + BASE + node*8*(2*LO+1);
  #pragma unroll
  for(int o=0;o<8;o++)
    #pragma unroll
    for(int m=0;m<2*LO+1;m++) op[o*(2*LO+1)+m] = acc[o][m];
}

struct WPtrs {
  const float* xx[3];
  const float* yx[3];
  const float* yy[3];
};

__global__ __launch_bounds__(256) void cg_kernel(
    const float* __restrict__ x0,const float* __restrict__ x1,const float* __restrict__ x2,
    const float* __restrict__ y, WPtrs w,
    float* __restrict__ p0, float* __restrict__ p1, float* __restrict__ p2)
{
  int node = blockIdx.x*256 + threadIdx.x;
  if(node >= NN) return;
  switch(blockIdx.y){     // heaviest first
    case 0: do_item<0,2>(node,x0,x1,x2,y,w.yy[2],p0); break;
    case 1: do_item<1,2>(node,x0,x1,x2,y,w.yx[2],p1); break;
    case 2: do_item<0,1>(node,x0,x1,x2,y,w.yy[1],p0); break;
    case 3: do_item<2,2>(node,x0,x1,x2,y,w.xx[2],p2); break;
    case 4: do_item<1,1>(node,x0,x1,x2,y,w.yx[1],p1); break;
    case 5: do_item<0,0>(node,x0,x1,x2,y,w.yy[0],p0); break;
    case 6: do_item<2,1>(node,x0,x1,x2,y,w.xx[1],p2); break;
    case 7: do_item<1,0>(node,x0,x1,x2,y,w.yx[0],p1); break;
    case 8: do_item<2,0>(node,x0,x1,x2,y,w.xx[0],p2); break;
  }
}

// ------------------------- elementwise sum of partials -> out -------------------------
__global__ __launch_bounds__(256) void sum_kernel(const float4* __restrict__ p0,
  const float4* __restrict__ p1, const float4* __restrict__ p2, float4* __restrict__ out)
{
  int i = blockIdx.x*256 + threadIdx.x;
  if(i >= NN*18) return;
  float4 a=p0[i], b=p1[i], c=p2[i];
  float4 r; r.x=a.x+b.x+c.x; r.y=a.y+b.y+c.y; r.z=a.z+b.z+c.z; r.w=a.w+b.w+c.w;
  out[i]=r;
}

// ------------------------- CSR build -------------------------
__global__ __launch_bounds__(256) void hist_kernel(const int* __restrict__ idx, int* __restrict__ cnt)
{
  int e = blockIdx.x*256 + threadIdx.x;
  if(e >= NE) return;
  atomicAdd(&cnt[idx[NE + e]], 1);
}

__global__ __launch_bounds__(1024) void scan_kernel(const int* __restrict__ cnt,
    int* __restrict__ offs, int* __restrict__ cur)
{
  __shared__ int wsum[16], wexc[16];
  __shared__ int carry, total;
  int tid = threadIdx.x;
  int lane = tid & 63, wid = tid >> 6;
  if(tid==0) carry = 0;
  __syncthreads();
  for(int base=0; base<NN; base+=1024){
    int i = base + tid;
    int v = (i<NN) ? cnt[i] : 0;
    int s = v;                                  // inclusive wave scan
    #pragma unroll
    for(int o=1;o<64;o<<=1){ int t=__shfl_up(s,o,64); if(lane>=o) s+=t; }
    if(lane==63) wsum[wid]=s;
    __syncthreads();
    if(tid<16){
      int w=wsum[tid], ws=w;
      #pragma unroll
      for(int o=1;o<16;o<<=1){ int t=__shfl_up(ws,o,16); if(tid>=o) ws+=t; }
      wexc[tid]=ws-w;
      if(tid==15) total=ws;
    }
    __syncthreads();
    int excl = s - v + wexc[wid];
    int myoff = carry + excl;
    if(i<NN){ offs[i]=myoff; cur[i]=myoff; }
    __syncthreads();
    if(tid==0) carry += total;
    __syncthreads();
  }
  if(tid==0) offs[NN]=carry;
}

__global__ __launch_bounds__(256) void scatter_kernel(const int* __restrict__ idx,
    const float* __restrict__ ev, int* __restrict__ cur,
    int* __restrict__ es, float2* __restrict__ ep)
{
  int e = blockIdx.x*256 + threadIdx.x;
  if(e >= NE) return;
  int dst = idx[NE + e];
  int pos = atomicAdd(&cur[dst], 1);
  es[pos] = idx[e];
  ep[pos] = make_float2(ev[2*e], ev[2*e+1]);
}

// ------------------------- gather: y[dst] = sum over in-edges (no atomics) -------------------------
__global__ __launch_bounds__(256) void gather_kernel(
    const float* __restrict__ x0, const float* __restrict__ x1, const float* __restrict__ x2,
    const int* __restrict__ es, const float2* __restrict__ ep, const int* __restrict__ offs,
    float* __restrict__ y)
{
  int t = blockIdx.x*256 + threadIdx.x;
  if(t >= NN*36) return;
  int node = t/36, j = t - node*36;
  const float* xp; int stride, base, d1;
  if(j<4)       { xp = x0 + j;      stride=4;  base=j;        d1=4;  }
  else if(j<16) { xp = x1 + (j-4);  stride=12; base=8+(j-4);  d1=12; }
  else          { xp = x2 + (j-16); stride=20; base=32+(j-16);d1=20; }
  float s0=0.f, s1=0.f;
  int k0=offs[node], k1=offs[node+1];
  for(int k=k0;k<k1;k++){
    int src = es[k];
    float2 e = ep[k];
    float xv = xp[src*stride];
    s0 = fmaf(e.x, xv, s0);
    s1 = fmaf(e.y, xv, s1);
  }
  float* yn = y + node*72;
  yn[base]    = s0;
  yn[base+d1] = s1;
}

extern "C" void kernel_launch(void* const* d_in, const int* in_sizes, int n_in,
                              void* d_out, int out_size, void* d_ws, size_t ws_size,
                              hipStream_t stream)
{
  const float* x0 = (const float*)d_in[0];
  const float* x1 = (const float*)d_in[1];
  const float* x2 = (const float*)d_in[2];
  const float* ev = (const float*)d_in[3];
  const int* idx  = (const int*)d_in[13];

  WPtrs w;
  for(int l=0;l<3;l++){
    w.xx[l] = (const float*)d_in[4+l];
    w.yx[l] = (const float*)d_in[7+l];
    w.yy[l] = (const float*)d_in[10+l];
  }

  // workspace layout
  float2* ep  = (float2*)d_ws;            // NE
  int*    es  = (int*)(ep + NE);          // NE
  int*    cnt = es + NE;                  // NN
  int*    offs= cnt + NN;                 // NN+1
  int*    cur = offs + NN + 1;            // NN
  float*  y   = (float*)(cur + NN);       // NN*72
  float*  p0  = y  + NN*72;               // NN*72
  float*  p1  = p0 + NN*72;               // NN*72
  float*  p2  = p1 + NN*72;               // NN*72

  hipMemsetAsync(cnt, 0, (size_t)NN*sizeof(int), stream);

  hist_kernel<<<(NE+255)/256, 256, 0, stream>>>(idx, cnt);
  scan_kernel<<<1, 1024, 0, stream>>>(cnt, offs, cur);
  scatter_kernel<<<(NE+255)/256, 256, 0, stream>>>(idx, ev, cur, es, ep);
  gather_kernel<<<(NN*36+255)/256, 256, 0, stream>>>(x0, x1, x2, es, ep, offs, y);

  dim3 g((NN+255)/256, 9);
  cg_kernel<<<g, 256, 0, stream>>>(x0, x1, x2, y, w, p0, p1, p2);

  sum_kernel<<<(NN*18+255)/256, 256, 0, stream>>>(
      (const float4*)p0, (const float4*)p1, (const float4*)p2, (float4*)d_out);
}

// Round 4
// 288.022 us; speedup vs baseline: 1.8660x; 1.6215x over previous
//
#include <hip/hip_runtime.h>
#include <stdint.h>

#define NN 30000
#define NE 480000

// ------------------------- compile-time Clebsch-Gordan -------------------------
constexpr double cfact(int n){ double r=1.0; for(int i=2;i<=n;i++) r*=(double)i; return r; }
constexpr double csqrt_(double x){ if(x<=0.0) return 0.0; double g = x<1.0?1.0:x; for(int i=0;i<200;i++) g = 0.5*(g + x/g); return g; }
constexpr double cg_coeff(int j1,int m1,int j2,int m2,int j,int m){
  if(m != m1+m2) return 0.0;
  int dj = j1-j2; if(dj<0) dj=-dj;
  if(j < dj || j > j1+j2) return 0.0;
  double pre = csqrt_((2*j+1)*cfact(j+j1-j2)*cfact(j-j1+j2)*cfact(j1+j2-j)/cfact(j1+j2+j+1));
  pre = pre * csqrt_(cfact(j+m)*cfact(j-m)*cfact(j1-m1)*cfact(j1+m1)*cfact(j2-m2)*cfact(j2+m2));
  double s = 0.0;
  for(int k=0;k<=j1+j2-j;k++){
    int d0=k, d1=j1+j2-j-k, d2=j1-m1-k, d3=j2+m2-k, d4=j-j2+m1+k, d5=j-j1-m2+k;
    if(d0<0||d1<0||d2<0||d3<0||d4<0||d5<0) continue;
    double term = 1.0/(cfact(d0)*cfact(d1)*cfact(d2)*cfact(d3)*cfact(d4)*cfact(d5));
    s += (k&1) ? -term : term;
  }
  return pre*s;
}

template<int L1,int L2,int LO> struct CGTab { float v[2*LO+1][2*L1+1][2*L2+1]; };

template<int L1,int L2,int LO>
constexpr CGTab<L1,L2,LO> make_cg(){
  CGTab<L1,L2,LO> t{};
  for(int m=-LO;m<=LO;m++)
    for(int p=-L1;p<=L1;p++)
      for(int q=-L2;q<=L2;q++)
        t.v[m+LO][p+L1][q+L2] = (float)cg_coeff(L1,p,L2,q,LO,m);
  return t;
}
template<int L1,int L2,int LO>
constexpr CGTab<L1,L2,LO> CG_TAB = make_cg<L1,L2,LO>();

// ------------------------- CG chunk (SoA, stride NN between rows) -------------------------
// A points at soa_base + node for the chunk's first row; row r -> A[r*NN].
// B likewise. W row-major [cat_channels][8]; row = wb + c*CB + d (wave-uniform).
template<int L1,int L2,int LO,int CA,int CB>
__device__ __forceinline__ void do_chunk(const float* __restrict__ A,
                                         const float* __restrict__ B,
                                         const float* __restrict__ W, int wb,
                                         float acc[8][2*LO+1])
{
  constexpr int MA=2*L1+1, MB=2*L2+1, MO=2*LO+1;
  float bv[CB][MB];
  #pragma unroll
  for(int d=0;d<CB;d++)
    #pragma unroll
    for(int q=0;q<MB;q++) bv[d][q] = B[(d*MB+q)*NN];
  #pragma unroll 1
  for(int c=0;c<CA;c++){
    float av[MA];
    #pragma unroll
    for(int p=0;p<MA;p++) av[p] = A[(c*MA+p)*NN];
    #pragma unroll
    for(int d=0;d<CB;d++){
      float T[MO];
      #pragma unroll
      for(int m=0;m<MO;m++) T[m]=0.f;
      #pragma unroll
      for(int m=0;m<MO;m++){
        #pragma unroll
        for(int p=0;p<MA;p++){
          #pragma unroll
          for(int q=0;q<MB;q++){
            const float cg = CG_TAB<L1,L2,LO>.v[m][p][q];   // compile-time const
            if(cg != 0.0f) T[m] = fmaf(cg*av[p], bv[d][q], T[m]);
          }
        }
      }
      const float* wr = W + (wb + c*CB + d)*8;               // wave-uniform -> s_load
      #pragma unroll
      for(int o=0;o<8;o++){
        float w = wr[o];
        #pragma unroll
        for(int m=0;m<MO;m++) acc[o][m] = fmaf(w, T[m], acc[o][m]);
      }
    }
  }
}

template<int LO,int CA,int CB>
__device__ __forceinline__ void run_chunks(
    const float* a0,const float* a1,const float* a2,
    const float* b0,const float* b1,const float* b2,
    const float* __restrict__ W, float acc[8][2*LO+1])
{
  int wb=0;
  if constexpr (LO==0){
    do_chunk<0,0,0,CA,CB>(a0,b0,W,wb,acc); wb+=CA*CB;
    do_chunk<1,1,0,CA,CB>(a1,b1,W,wb,acc); wb+=CA*CB;
    do_chunk<2,2,0,CA,CB>(a2,b2,W,wb,acc);
  } else if constexpr (LO==1){
    do_chunk<0,1,1,CA,CB>(a0,b1,W,wb,acc); wb+=CA*CB;
    do_chunk<1,0,1,CA,CB>(a1,b0,W,wb,acc); wb+=CA*CB;
    do_chunk<1,1,1,CA,CB>(a1,b1,W,wb,acc); wb+=CA*CB;
    do_chunk<1,2,1,CA,CB>(a1,b2,W,wb,acc); wb+=CA*CB;
    do_chunk<2,1,1,CA,CB>(a2,b1,W,wb,acc); wb+=CA*CB;
    do_chunk<2,2,1,CA,CB>(a2,b2,W,wb,acc);
  } else {
    do_chunk<0,2,2,CA,CB>(a0,b2,W,wb,acc); wb+=CA*CB;
    do_chunk<1,1,2,CA,CB>(a1,b1,W,wb,acc); wb+=CA*CB;
    do_chunk<1,2,2,CA,CB>(a1,b2,W,wb,acc); wb+=CA*CB;
    do_chunk<2,0,2,CA,CB>(a2,b0,W,wb,acc); wb+=CA*CB;
    do_chunk<2,1,2,CA,CB>(a2,b1,W,wb,acc); wb+=CA*CB;
    do_chunk<2,2,2,CA,CB>(a2,b2,W,wb,acc);
  }
}

// One thread = one (node, PROD, LO). y and xs are SoA (row*NN + node).
// y rows: l0 @0 (8), l1 @8 (24), l2 @32 (40).  xs rows: l0 @0 (4), l1 @4 (12), l2 @16 (20).
// Partials also SoA: rows OB + o*(2LO+1)+m.
template<int PROD,int LO>
__device__ __forceinline__ void do_item(int node,
    const float* __restrict__ xs, const float* __restrict__ y,
    const float* __restrict__ W, float* __restrict__ p)
{
  constexpr int CA = (PROD==2)?4:8;
  constexpr int CB = (PROD==0)?8:4;
  const float *a0,*a1,*a2,*b0,*b1,*b2;
  if constexpr (PROD==2){ a0 = xs + node; a1 = xs + 4*NN + node; a2 = xs + 16*NN + node; }
  else                  { a0 = y  + node; a1 = y  + 8*NN + node; a2 = y  + 32*NN + node; }
  if constexpr (PROD==0){ b0 = y  + node; b1 = y  + 8*NN + node; b2 = y  + 32*NN + node; }
  else                  { b0 = xs + node; b1 = xs + 4*NN + node; b2 = xs + 16*NN + node; }

  float acc[8][2*LO+1];
  #pragma unroll
  for(int o=0;o<8;o++)
    #pragma unroll
    for(int m=0;m<2*LO+1;m++) acc[o][m]=0.f;

  run_chunks<LO,CA,CB>(a0,a1,a2,b0,b1,b2,W,acc);

  constexpr int OB = (LO==0)?0:((LO==1)?8:32);
  float* op = p + OB*NN + node;
  #pragma unroll
  for(int o=0;o<8;o++)
    #pragma unroll
    for(int m=0;m<2*LO+1;m++) op[(o*(2*LO+1)+m)*NN] = acc[o][m];
}

struct WPtrs {
  const float* xx[3];
  const float* yx[3];
  const float* yy[3];
};

__global__ __launch_bounds__(256) void cg_kernel(
    const float* __restrict__ xs, const float* __restrict__ y, WPtrs w,
    float* __restrict__ p0, float* __restrict__ p1, float* __restrict__ p2)
{
  int node = blockIdx.x*256 + threadIdx.x;
  if(node >= NN) return;
  switch(blockIdx.y){     // heaviest first
    case 0: do_item<0,2>(node,xs,y,w.yy[2],p0); break;
    case 1: do_item<1,2>(node,xs,y,w.yx[2],p1); break;
    case 2: do_item<0,1>(node,xs,y,w.yy[1],p0); break;
    case 3: do_item<2,2>(node,xs,y,w.xx[2],p2); break;
    case 4: do_item<1,1>(node,xs,y,w.yx[1],p1); break;
    case 5: do_item<0,0>(node,xs,y,w.yy[0],p0); break;
    case 6: do_item<2,1>(node,xs,y,w.xx[1],p2); break;
    case 7: do_item<1,0>(node,xs,y,w.yx[0],p1); break;
    case 8: do_item<2,0>(node,xs,y,w.xx[0],p2); break;
  }
}

// ------------------------- sum partials (SoA) -> out (AoS, reference layout) ------------
__global__ __launch_bounds__(256) void sum_kernel(const float* __restrict__ p0,
  const float* __restrict__ p1, const float* __restrict__ p2, float* __restrict__ out)
{
  int i = blockIdx.x*256 + threadIdx.x;
  if(i >= NN*72) return;
  int row, node;
  if(i < NN*8)       { node = i>>3;          row = i&7; }
  else if(i < NN*32) { int r=i-NN*8;  node=r/24; row = 8  + (r - node*24); }
  else               { int r=i-NN*32; node=r/40; row = 32 + (r - node*40); }
  int pi = row*NN + node;
  out[i] = p0[pi] + p1[pi] + p2[pi];
}

// ------------------------- CSR build -------------------------
__global__ __launch_bounds__(256) void hist_kernel(const int* __restrict__ idx, int* __restrict__ cnt)
{
  int e = blockIdx.x*256 + threadIdx.x;
  if(e >= NE) return;
  atomicAdd(&cnt[idx[NE + e]], 1);
}

// 64 blocks x 256 threads, 2 elements/thread -> block-local exclusive scan + block totals
__global__ __launch_bounds__(256) void scan1_kernel(const int* __restrict__ cnt,
    int* __restrict__ offs, int* __restrict__ bt)
{
  __shared__ int wsum[4], wexc[4];
  int b = blockIdx.x, tid = threadIdx.x;
  int lane = tid & 63, wid = tid >> 6;
  int i0 = b*512 + tid*2;
  int v0 = (i0   < NN) ? cnt[i0]   : 0;
  int v1 = (i0+1 < NN) ? cnt[i0+1] : 0;
  int v = v0+v1, s = v;
  #pragma unroll
  for(int o=1;o<64;o<<=1){ int t=__shfl_up(s,o,64); if(lane>=o) s+=t; }
  if(lane==63) wsum[wid]=s;
  __syncthreads();
  if(tid<4){
    int wv=wsum[tid], x=wv;
    #pragma unroll
    for(int o=1;o<4;o<<=1){ int t=__shfl_up(x,o,4); if(tid>=o) x+=t; }
    wexc[tid]=x-wv;
    if(tid==3) bt[b]=x;
  }
  __syncthreads();
  int excl = s - v + wexc[wid];
  if(i0   < NN) offs[i0]   = excl;
  if(i0+1 < NN) offs[i0+1] = excl + v0;
}

__global__ __launch_bounds__(64) void scan2_kernel(int* __restrict__ bt,
    int* __restrict__ bte, int* __restrict__ offs)
{
  int tid = threadIdx.x;
  int v = bt[tid], s = v;
  #pragma unroll
  for(int o=1;o<64;o<<=1){ int t=__shfl_up(s,o,64); if(tid>=o) s+=t; }
  bte[tid] = s - v;
  if(tid==63) offs[NN] = s;
}

__global__ __launch_bounds__(512) void scan3_kernel(int* __restrict__ offs,
    const int* __restrict__ bte, int* __restrict__ cur)
{
  int i = blockIdx.x*512 + threadIdx.x;
  if(i >= NN) return;
  int o = offs[i] + bte[blockIdx.x];
  offs[i] = o;
  cur[i]  = o;
}

// 16B edge record
__global__ __launch_bounds__(256) void scatter_kernel(const int* __restrict__ idx,
    const float* __restrict__ ev, int* __restrict__ cur, float4* __restrict__ edges)
{
  int e = blockIdx.x*256 + threadIdx.x;
  if(e >= NE) return;
  int dst = idx[NE + e];
  int pos = atomicAdd(&cur[dst], 1);
  float4 r;
  r.x = __int_as_float(idx[e]);
  r.y = ev[2*e];
  r.z = ev[2*e+1];
  r.w = 0.f;
  edges[pos] = r;
}

// ------------------------- x AoS -> SoA transpose -------------------------
__global__ __launch_bounds__(256) void xpose_kernel(
    const float* __restrict__ x0, const float* __restrict__ x1, const float* __restrict__ x2,
    float* __restrict__ xs)
{
  int t = blockIdx.x*256 + threadIdx.x;    // t = row*NN + node
  if(t >= NN*36) return;
  int row = t / NN, node = t - row*NN;
  float v;
  if(row < 4)       v = x0[node*4  + row];
  else if(row < 16) v = x1[node*12 + (row-4)];
  else              v = x2[node*20 + (row-16)];
  xs[t] = v;
}

// ------------------------- gather: one thread per (node, c) -------------------------
// writes y SoA rows: l0: ech*4+c ; l1: 8+(ech*4+c)*3+m ; l2: 32+(ech*4+c)*5+m
__global__ __launch_bounds__(256) void gather_kernel(
    const float* __restrict__ x0, const float* __restrict__ x1, const float* __restrict__ x2,
    const float4* __restrict__ edges, const int* __restrict__ offs,
    float* __restrict__ y)
{
  int t = blockIdx.x*256 + threadIdx.x;
  if(t >= NN*4) return;
  int node = t >> 2, c = t & 3;
  float a0[2]={0.f,0.f};
  float a1[2][3]={}, a2[2][5]={};
  int k0 = offs[node], k1 = offs[node+1];
  for(int k=k0;k<k1;k++){
    float4 ed = edges[k];
    int src = __float_as_int(ed.x);
    float e0 = ed.y, e1 = ed.z;
    float v0 = x0[src*4 + c];
    const float* p1 = x1 + src*12 + c*3;
    const float* p2 = x2 + src*20 + c*5;
    a0[0] = fmaf(e0, v0, a0[0]);
    a0[1] = fmaf(e1, v0, a0[1]);
    #pragma unroll
    for(int m=0;m<3;m++){ float v=p1[m]; a1[0][m]=fmaf(e0,v,a1[0][m]); a1[1][m]=fmaf(e1,v,a1[1][m]); }
    #pragma unroll
    for(int m=0;m<5;m++){ float v=p2[m]; a2[0][m]=fmaf(e0,v,a2[0][m]); a2[1][m]=fmaf(e1,v,a2[1][m]); }
  }
  #pragma unroll
  for(int ech=0;ech<2;ech++){
    int ch = ech*4 + c;
    y[ch*NN + node] = a0[ech];
    #pragma unroll
    for(int m=0;m<3;m++) y[(8  + ch*3 + m)*NN + node] = a1[ech][m];
    #pragma unroll
    for(int m=0;m<5;m++) y[(32 + ch*5 + m)*NN + node] = a2[ech][m];
  }
}

extern "C" void kernel_launch(void* const* d_in, const int* in_sizes, int n_in,
                              void* d_out, int out_size, void* d_ws, size_t ws_size,
                              hipStream_t stream)
{
  const float* x0 = (const float*)d_in[0];
  const float* x1 = (const float*)d_in[1];
  const float* x2 = (const float*)d_in[2];
  const float* ev = (const float*)d_in[3];
  const int* idx  = (const int*)d_in[13];

  WPtrs w;
  for(int l=0;l<3;l++){
    w.xx[l] = (const float*)d_in[4+l];
    w.yx[l] = (const float*)d_in[7+l];
    w.yy[l] = (const float*)d_in[10+l];
  }

  // workspace layout
  float4* edges = (float4*)d_ws;            // NE  (7.68 MB)
  int*    cnt   = (int*)(edges + NE);       // NN
  int*    offs  = cnt + NN;                 // NN+1
  int*    cur   = offs + NN + 1;            // NN
  int*    bt    = cur + NN;                 // 64
  int*    bte   = bt + 64;                  // 64
  float*  xs    = (float*)(bte + 64);       // NN*36 (4.32 MB)
  float*  y     = xs + NN*36;               // NN*72 (8.64 MB)
  float*  p0    = y  + NN*72;               // NN*72
  float*  p1    = p0 + NN*72;               // NN*72
  float*  p2    = p1 + NN*72;               // NN*72

  hipMemsetAsync(cnt, 0, (size_t)NN*sizeof(int), stream);

  hist_kernel<<<(NE+255)/256, 256, 0, stream>>>(idx, cnt);
  scan1_kernel<<<64, 256, 0, stream>>>(cnt, offs, bt);
  scan2_kernel<<<1, 64, 0, stream>>>(bt, bte, offs);
  scan3_kernel<<<64, 512, 0, stream>>>(offs, bte, cur);
  scatter_kernel<<<(NE+255)/256, 256, 0, stream>>>(idx, ev, cur, edges);
  xpose_kernel<<<(NN*36+255)/256, 256, 0, stream>>>(x0, x1, x2, xs);
  gather_kernel<<<(NN*4+255)/256, 256, 0, stream>>>(x0, x1, x2, edges, offs, y);

  dim3 g((NN+255)/256, 9);
  cg_kernel<<<g, 256, 0, stream>>>(xs, y, w, p0, p1, p2);

  sum_kernel<<<(NN*72+255)/256, 256, 0, stream>>>(p0, p1, p2, (float*)d_out);
}